// Round 7
// baseline (189.402 us; speedup 1.0000x reference)
//
#include <hip/hip_runtime.h>
#include <stdint.h>

// ---------------------------------------------------------------------------
// MultiHeadAttentionCrossWithWeights: B=8, Tq=448, Tk=1500, D=1280, H=20, Dh=64
// Round 7: prep fixed (grid-stride cvt @ 32B/lane; vt with float4 loads,
// swizzled stride-132 bf16 LDS, 16B stores). GEMM gets dbuf + counted vmcnt
// (grid=280 -> 1 block/CU -> barrier drain was fully exposed).
// attn (r6 k-split) and weights unchanged.
// ---------------------------------------------------------------------------

typedef short bf16x8 __attribute__((ext_vector_type(8)));   // 8 bf16 in 4 VGPRs
typedef float f32x4  __attribute__((ext_vector_type(4)));

#define VMCNT(n) asm volatile("s_waitcnt vmcnt(" #n ")" ::: "memory")

__device__ __forceinline__ unsigned short f2bf(float f) {
  union { float f; unsigned int u; } c; c.f = f;
  unsigned int u = c.u;
  unsigned int r = (u + 0x7FFFu + ((u >> 16) & 1u)) >> 16;  // RNE
  return (unsigned short)r;
}

__device__ __forceinline__ float exp2_hw(float x) {
  float r;
  asm("v_exp_f32 %0, %1" : "=v"(r) : "v"(x));   // r = 2^x
  return r;
}

// async global->LDS, 16B per lane. LDS dest is wave-uniform base; HW adds lane*16.
__device__ __forceinline__ void gld_lds16(const void* g, void* l) {
  __builtin_amdgcn_global_load_lds(
      (__attribute__((address_space(1))) void*)g,
      (__attribute__((address_space(3))) void*)l, 16, 0, 0);
}

// XOR-swizzled read inside a [rows][64 bf16] tile (128B rows)
__device__ __forceinline__ bf16x8 ldfrag(const void* base, int row, int c16) {
  return *reinterpret_cast<const bf16x8*>(
      reinterpret_cast<const char*>(base) + (row << 7) + (((c16 ^ (row & 7))) << 4));
}
// XOR-swizzled read inside a [rows][128 bf16] tile (256B rows)
__device__ __forceinline__ bf16x8 ldfragV(const void* base, int row, int c16) {
  return *reinterpret_cast<const bf16x8*>(
      reinterpret_cast<const char*>(base) + (row << 8) + (((c16 ^ (row & 15))) << 4));
}

// ---------------------------------------------------------------------------
// grid-stride f32->bf16 convert for x, Wq, Wo, k (dests contiguous in ws).
// 8 floats per lane-iter: 32B load, 16B store.
__global__ __launch_bounds__(256) void cvt_kernel(const float* __restrict__ s0,
                                                  const float* __restrict__ s1,
                                                  const float* __restrict__ s2,
                                                  const float* __restrict__ s3,
                                                  unsigned short* __restrict__ dst) {
  const int n0 = 573440, n1 = 204800, n2 = 204800;   // 8-float chunks
  const int total = 2903040;                          // + n3 = 1920000
  for (int i = blockIdx.x * 256 + threadIdx.x; i < total; i += gridDim.x * 256) {
    const float* src; int j = i;
    if (j < n0)               { src = s0; }
    else if ((j -= n0) < n1)  { src = s1; }
    else if ((j -= n1) < n2)  { src = s2; }
    else                      { j -= n2; src = s3; }
    float4 a = *reinterpret_cast<const float4*>(src + (size_t)j * 8);
    float4 b = *reinterpret_cast<const float4*>(src + (size_t)j * 8 + 4);
    uint4 o;
    o.x = f2bf(a.x) | ((unsigned int)f2bf(a.y) << 16);
    o.y = f2bf(a.z) | ((unsigned int)f2bf(a.w) << 16);
    o.z = f2bf(b.x) | ((unsigned int)f2bf(b.y) << 16);
    o.w = f2bf(b.z) | ((unsigned int)f2bf(b.w) << 16);
    *reinterpret_cast<uint4*>(dst + (size_t)i * 8) = o;
  }
}

// ---------------------------------------------------------------------------
// v (b,tk,1280) f32 -> vbt (b,h,64,1536) bf16 transposed per head, zero-padded.
// Block = (b,h,kt128). float4 loads; bf16 LDS [128 k][64 d], row stride 132B,
// d-chunk XOR swizzle; transposed reads ~4-way conflict; ushort8 stores.
__global__ __launch_bounds__(256) void vt_kernel(const float* __restrict__ v,
                                                 unsigned short* __restrict__ vbt) {
  __shared__ __attribute__((aligned(16))) char T[128 * 132];
  int blk = blockIdx.x;
  const int kt = blk % 12; blk /= 12;
  const int h = blk % 20; const int b = blk / 20;
  const int t = threadIdx.x;

  // ---- load + convert + swizzled LDS store
  const int c4 = t & 15;          // float4 col: d = c4*4..+3
  const int r  = t >> 4;          // row within 16-row group
#pragma unroll
  for (int p = 0; p < 8; ++p) {
    const int k = p * 16 + r;
    const int gtk = kt * 128 + k;
    float4 a = {0.f, 0.f, 0.f, 0.f};
    if (gtk < 1500)
      a = *reinterpret_cast<const float4*>(v + (size_t)(b * 1500 + gtk) * 1280 + h * 64 + c4 * 4);
    unsigned int lo = f2bf(a.x) | ((unsigned int)f2bf(a.y) << 16);
    unsigned int hi = f2bf(a.z) | ((unsigned int)f2bf(a.w) << 16);
    char* base = T + k * 132 + ((c4 ^ (k & 15)) << 3);
    *reinterpret_cast<unsigned int*>(base)     = lo;
    *reinterpret_cast<unsigned int*>(base + 4) = hi;
  }
  __syncthreads();

  // ---- transposed read + pack + coalesced 16B store
  const int kc = t & 15;          // 8-k output chunk
#pragma unroll
  for (int p = 0; p < 4; ++p) {
    const int d = p * 16 + (t >> 4);
    unsigned short r8[8];
#pragma unroll
    for (int j = 0; j < 8; ++j) {
      const int k = kc * 8 + j;
      r8[j] = *reinterpret_cast<const unsigned short*>(
          T + k * 132 + (((d >> 2) ^ (k & 15)) << 3) + ((d & 3) << 1));
    }
    uint4 o;
    o.x = r8[0] | ((unsigned int)r8[1] << 16);
    o.y = r8[2] | ((unsigned int)r8[3] << 16);
    o.z = r8[4] | ((unsigned int)r8[5] << 16);
    o.w = r8[6] | ((unsigned int)r8[7] << 16);
    *reinterpret_cast<uint4*>(
        vbt + ((size_t)((b * 20 + h) * 64 + d)) * 1536 + kt * 128 + kc * 8) = o;
  }
}

// ---------------------------------------------------------------------------
// GEMM (bt form): C[m][n] = sum_k A[m,k]*B[n,k]; epi 0: bf16 (C+bias)*scale, 1: f32
// 128x128 tile, BK=64, 4 waves; DOUBLE-BUFFERED LDS + counted vmcnt.
template <int EPI>
__global__ __launch_bounds__(256) void gemm_bt(const unsigned short* __restrict__ A,
                                               const unsigned short* __restrict__ Bm,
                                               const float* __restrict__ bias,
                                               void* __restrict__ Cout,
                                               int M, int N, int K, float scale) {
  __shared__ __attribute__((aligned(16))) unsigned short As[2][128 * 64];
  __shared__ __attribute__((aligned(16))) unsigned short Bs[2][128 * 64];
  const int tid = threadIdx.x;
  const int w = tid >> 6, lane = tid & 63;
  const int l15 = lane & 15, l4 = lane >> 4;
  const int nBlk = N >> 7;
  const int cpx = gridDim.x >> 3;
  const int bid = (blockIdx.x & 7) * cpx + (blockIdx.x >> 3);
  const int bm = bid / nBlk, bn = bid % nBlk;
  const int m0 = bm << 7, n0 = bn << 7;
  const int wr = (w >> 1) << 6, wc = (w & 1) << 6;

  f32x4 acc[4][4] = {};

  auto stage = [&](int kt, int buf) {
    const int koff = kt << 6;
#pragma unroll
    for (int r = 0; r < 4; ++r) {
      const int base = (((w << 2) + r) << 10);
      const int p = base + (lane << 4);
      const int row = p >> 7;
      const int cb = (p & 127) >> 1;
      gld_lds16(A  + ((size_t)(m0 + row) * K + koff + cb), (char*)As[buf] + base);
      gld_lds16(Bm + ((size_t)(n0 + row) * K + koff + cb), (char*)Bs[buf] + base);
    }
  };

  const int nKt = K >> 6;
  stage(0, 0);
  VMCNT(0);
  __builtin_amdgcn_s_barrier();

  for (int kt = 0; kt < nKt; ++kt) {
    const int buf = kt & 1;
    if (kt + 1 < nKt) {
      stage(kt + 1, buf ^ 1);
      VMCNT(8);                       // prev tile's 8 DMAs landed; 8 in flight
    } else {
      VMCNT(0);
    }
    __builtin_amdgcn_s_barrier();

    __builtin_amdgcn_s_setprio(1);
#pragma unroll
    for (int kk = 0; kk < 64; kk += 32) {
      bf16x8 af[4], bfr[4];
#pragma unroll
      for (int mi = 0; mi < 4; ++mi)
        af[mi] = *reinterpret_cast<const bf16x8*>(&As[buf][(wr + mi * 16 + l15) * 64 + kk + l4 * 8]);
#pragma unroll
      for (int ni = 0; ni < 4; ++ni)
        bfr[ni] = *reinterpret_cast<const bf16x8*>(&Bs[buf][(wc + ni * 16 + l15) * 64 + kk + l4 * 8]);
#pragma unroll
      for (int mi = 0; mi < 4; ++mi)
#pragma unroll
        for (int ni = 0; ni < 4; ++ni)
          acc[mi][ni] = __builtin_amdgcn_mfma_f32_16x16x32_bf16(af[mi], bfr[ni], acc[mi][ni], 0, 0, 0);
    }
    __builtin_amdgcn_s_setprio(0);
    __builtin_amdgcn_s_barrier();     // compute done before buf is re-staged
  }

#pragma unroll
  for (int ni = 0; ni < 4; ++ni) {
    const int n = n0 + wc + ni * 16 + l15;
    const float bv = bias[n];
#pragma unroll
    for (int mi = 0; mi < 4; ++mi) {
#pragma unroll
      for (int i = 0; i < 4; ++i) {
        const int m = m0 + wr + mi * 16 + l4 * 4 + i;
        float vv = (acc[mi][ni][i] + bv) * scale;
        if (EPI == 0)
          ((unsigned short*)Cout)[(size_t)m * N + n] = f2bf(vv);
        else
          ((float*)Cout)[(size_t)m * N + n] = vv;
      }
    }
  }
}

// ---------------------------------------------------------------------------
// Flash attention, k-split structure (r6, verified).
__global__ __launch_bounds__(256, 2) void attn_kernel(const unsigned short* __restrict__ Qg,
                                                      const unsigned short* __restrict__ Kg,
                                                      const unsigned short* __restrict__ Vtg,
                                                      unsigned short* __restrict__ Og,
                                                      float* __restrict__ ML) {
  // 80KB: K0 16K | K1 16K | V0 16K | V1 16K | P 16K (4KB/wave)
  __shared__ __attribute__((aligned(16))) char smem[81920];
  char* const K0 = smem;
  char* const K1 = smem + 16384;
  char* const V0 = smem + 32768;
  char* const V1 = smem + 49152;
  char* const Pw = smem + 65536 + (threadIdx.x >> 6) * 4096;

  const int tid = threadIdx.x;
  const int w = tid >> 6, lane = tid & 63;
  const int l15 = lane & 15, l4 = lane >> 4;
  int bid = (blockIdx.x & 7) * 140 + (blockIdx.x >> 3);
  const int qt = bid % 7; bid /= 7;
  const int h = bid % 20; const int b = bid / 20;
  const int tq0 = qt << 6;

  const int srK = lane >> 3;
  const int scK = ((lane & 7) ^ srK) << 3;
  const int vr4 = lane >> 4;
  const size_t vbase = ((size_t)(b * 20 + h)) * 64 * 1536;

  bf16x8 qreg[4][2];
#pragma unroll
  for (int qg = 0; qg < 4; ++qg) {
    const unsigned short* qp =
        Qg + (size_t)(b * 448 + tq0 + qg * 16 + l15) * 1280 + h * 64 + l4 * 8;
    qreg[qg][0] = *reinterpret_cast<const bf16x8*>(qp);
    qreg[qg][1] = *reinterpret_cast<const bf16x8*>(qp + 32);
  }

  auto stage = [&](int k0, char* Kd, char* Vd) {
#pragma unroll
    for (int c = 0; c < 4; ++c) {
      const int ch = (w << 2) + c;
      int tk = k0 + ch * 8 + srK; if (tk > 1499) tk = 1499;
      gld_lds16(Kg + ((size_t)(b * 1500 + tk)) * 1280 + h * 64 + scK, Kd + ch * 1024);
    }
#pragma unroll
    for (int c = 0; c < 4; ++c) {
      const int ch = (w << 2) + c;
      const int d = (ch << 2) + vr4;
      const int col = ((lane & 15) ^ ((c << 2) + vr4)) << 3;
      gld_lds16(Vtg + vbase + (size_t)d * 1536 + k0 + col, Vd + ch * 1024);
    }
  };

  stage(0, K0, V0);
  VMCNT(0);
  __builtin_amdgcn_s_barrier();

  float l_p[4] = {0.f, 0.f, 0.f, 0.f};
  f32x4 o_acc[4][4] = {};

  for (int kt = 0; kt < 12; ++kt) {
    const int cur = kt & 1;
    const char* Kb = cur ? K1 : K0;
    const char* Vb = cur ? V1 : V0;

    if (kt < 11) {
      stage((kt + 1) << 7, cur ? K0 : K1, cur ? V0 : V1);
      VMCNT(8);
    } else {
      VMCNT(0);
    }
    __builtin_amdgcn_s_barrier();

    f32x4 s[2][4] = {};
    __builtin_amdgcn_s_setprio(1);
#pragma unroll
    for (int h2 = 0; h2 < 2; ++h2) {
      bf16x8 kf0 = ldfrag(Kb, (w << 5) + l15,      (h2 << 2) + l4);
      bf16x8 kf1 = ldfrag(Kb, (w << 5) + 16 + l15, (h2 << 2) + l4);
#pragma unroll
      for (int qg = 0; qg < 4; ++qg)
        s[0][qg] = __builtin_amdgcn_mfma_f32_16x16x32_bf16(kf0, qreg[qg][h2], s[0][qg], 0, 0, 0);
#pragma unroll
      for (int qg = 0; qg < 4; ++qg)
        s[1][qg] = __builtin_amdgcn_mfma_f32_16x16x32_bf16(kf1, qreg[qg][h2], s[1][qg], 0, 0, 0);
    }
    __builtin_amdgcn_s_setprio(0);

    if (kt == 11) {
#pragma unroll
      for (int kg = 0; kg < 2; ++kg)
#pragma unroll
        for (int i = 0; i < 4; ++i)
          if ((w << 5) + (kg << 4) + (l4 << 2) + i >= 92) {
#pragma unroll
            for (int qg = 0; qg < 4; ++qg) s[kg][qg][i] = -1e30f;
          }
    }

#pragma unroll
    for (int kg = 0; kg < 2; ++kg)
#pragma unroll
      for (int qg = 0; qg < 4; ++qg) {
#pragma unroll
        for (int i = 0; i < 4; ++i) {
          float e = exp2_hw(fmaf(s[kg][qg][i], 1.44269504f, -17.31234049f));
          s[kg][qg][i] = e;
          l_p[qg] += e;
        }
        unsigned int u0, u1;
        asm("v_cvt_pk_bf16_f32 %0, %1, %2" : "=v"(u0) : "v"(s[kg][qg][0]), "v"(s[kg][qg][1]));
        asm("v_cvt_pk_bf16_f32 %0, %1, %2" : "=v"(u1) : "v"(s[kg][qg][2]), "v"(s[kg][qg][3]));
        unsigned long long u01 = ((unsigned long long)u1 << 32) | u0;
        *reinterpret_cast<unsigned long long*>(
            Pw + (qg << 10) + (((kg << 1) + (l4 >> 1)) << 8) + (l15 << 4) + ((l4 & 1) << 3)) = u01;
      }

    __builtin_amdgcn_s_setprio(1);
    bf16x8 bv[4];
#pragma unroll
    for (int dg = 0; dg < 4; ++dg)
      bv[dg] = ldfragV(Vb, (dg << 4) + l15, (w << 2) + l4);
#pragma unroll
    for (int qg = 0; qg < 4; ++qg) {
      bf16x8 ap = *reinterpret_cast<const bf16x8*>(Pw + (qg << 10) + (lane << 4));
#pragma unroll
      for (int dg = 0; dg < 4; ++dg)
        o_acc[qg][dg] = __builtin_amdgcn_mfma_f32_16x16x32_bf16(ap, bv[dg], o_acc[qg][dg], 0, 0, 0);
    }
    __builtin_amdgcn_s_setprio(0);
    __builtin_amdgcn_s_barrier();
  }

  // ---- epilogue: cross-wave O and l reduction
#pragma unroll
  for (int qg = 0; qg < 4; ++qg)
#pragma unroll
    for (int dg = 0; dg < 4; ++dg)
      *reinterpret_cast<f32x4*>(smem + (w << 14) + (((qg << 2) + dg) << 10) + (lane << 4)) =
          o_acc[qg][dg];

  float* Lb = (float*)(smem + 65536);
  float lw[4];
#pragma unroll
  for (int qg = 0; qg < 4; ++qg) {
    float t = l_p[qg] + __shfl_xor(l_p[qg], 16);
    t += __shfl_xor(t, 32);
    lw[qg] = t;
  }
  if (l4 == 0) {
#pragma unroll
    for (int qg = 0; qg < 4; ++qg) Lb[(w << 6) + (qg << 4) + l15] = lw[qg];
  }
  __syncthreads();

  float ltot = 0.f;
#pragma unroll
  for (int w2 = 0; w2 < 4; ++w2) ltot += Lb[(w2 << 6) + (w << 4) + l15];
  const float rr = 1.f / ltot;
  float rinv4[4], lt4[4];
#pragma unroll
  for (int i = 0; i < 4; ++i) {
    rinv4[i] = __shfl(rr,   (l4 << 2) + i);
    lt4[i]   = __shfl(ltot, (l4 << 2) + i);
  }
#pragma unroll
  for (int dg = 0; dg < 4; ++dg) {
    f32x4 t = *reinterpret_cast<const f32x4*>(
        smem + (((w << 2) + dg) << 10) + (lane << 4));
#pragma unroll
    for (int w2 = 1; w2 < 4; ++w2)
      t += *reinterpret_cast<const f32x4*>(
          smem + (w2 << 14) + (((w << 2) + dg) << 10) + (lane << 4));
#pragma unroll
    for (int i = 0; i < 4; ++i)
      Og[(size_t)(b * 448 + tq0 + (w << 4) + (l4 << 2) + i) * 1280 + h * 64 + (dg << 4) + l15] =
          f2bf(t[i] * rinv4[i]);
  }
  if (l15 == 0) {
#pragma unroll
    for (int i = 0; i < 4; ++i) {
      size_t idx = (size_t)(b * 20 + h) * 448 + tq0 + (w << 4) + (l4 << 2) + i;
      ML[idx * 2]     = 12.0f;
      ML[idx * 2 + 1] = lt4[i];
    }
  }
}

// ---------------------------------------------------------------------------
// Alignment weights: recompute QK for heads {4,7,11}, w = exp(s-m)/l (f32).
__global__ __launch_bounds__(256) void weights_kernel(const unsigned short* __restrict__ Qg,
                                                      const unsigned short* __restrict__ Kg,
                                                      const float* __restrict__ ML,
                                                      float* __restrict__ Wout) {
  __shared__ __attribute__((aligned(16))) unsigned short Ks0[64 * 64];
  __shared__ __attribute__((aligned(16))) unsigned short Ks1[64 * 64];
  const int tid = threadIdx.x;
  const int w = tid >> 6, lane = tid & 63;
  const int l15 = lane & 15, l4 = lane >> 4;
  int bid = (blockIdx.x & 7) * 21 + (blockIdx.x >> 3);
  const int qt = bid % 7; bid /= 7;
  const int ha = bid % 3; const int b = bid / 3;
  const int h = (ha == 0) ? 4 : (ha == 1) ? 7 : 11;
  const int tq0 = qt << 6;

  const int srow = lane >> 3;
  const int scol = ((lane & 7) ^ srow) << 3;

  const unsigned short* qptr =
      Qg + (size_t)(b * 448 + tq0 + w * 16 + l15) * 1280 + h * 64 + l4 * 8;
  bf16x8 qreg[2];
  qreg[0] = *reinterpret_cast<const bf16x8*>(qptr);
  qreg[1] = *reinterpret_cast<const bf16x8*>(qptr + 32);

#pragma unroll
  for (int c = 0; c < 2; ++c) {
    const int ch = w * 2 + c;
    const int row = ch * 8 + srow;
    int tk = row; if (tk > 1499) tk = 1499;
    gld_lds16(Kg + ((size_t)(b * 1500 + tk) * 1280 + h * 64 + scol), (char*)Ks0 + ch * 1024);
  }
  VMCNT(0);
  __builtin_amdgcn_s_barrier();

  float m_r[4], rinv[4];
#pragma unroll
  for (int i = 0; i < 4; ++i) {
    size_t idx = (size_t)(b * 20 + h) * 448 + tq0 + w * 16 + l4 * 4 + i;
    m_r[i]  = ML[idx * 2];
    rinv[i] = 1.f / ML[idx * 2 + 1];
  }
  float* wbase = Wout + ((size_t)(b * 3 + ha) * 448 + tq0) * 1500;

  for (int kt = 0; kt < 24; ++kt) {
    const int cur = kt & 1;
    const unsigned short* Kb = cur ? Ks1 : Ks0;
    unsigned short* Kn = cur ? Ks0 : Ks1;
    if (kt < 23) {
      const int k0n = (kt + 1) << 6;
#pragma unroll
      for (int c = 0; c < 2; ++c) {
        const int ch = w * 2 + c;
        const int row = ch * 8 + srow;
        int tk = k0n + row; if (tk > 1499) tk = 1499;
        gld_lds16(Kg + ((size_t)(b * 1500 + tk) * 1280 + h * 64 + scol), (char*)Kn + ch * 1024);
      }
      VMCNT(2);
    } else {
      VMCNT(0);
    }
    __builtin_amdgcn_s_barrier();

    f32x4 s[4] = {};
    __builtin_amdgcn_s_setprio(1);
#pragma unroll
    for (int h2 = 0; h2 < 2; ++h2) {
#pragma unroll
      for (int ni = 0; ni < 4; ++ni) {
        bf16x8 bk = ldfrag(Kb, ni * 16 + l15, h2 * 4 + l4);
        s[ni] = __builtin_amdgcn_mfma_f32_16x16x32_bf16(qreg[h2], bk, s[ni], 0, 0, 0);
      }
    }
    __builtin_amdgcn_s_setprio(0);

    const int k0 = kt << 6;
#pragma unroll
    for (int ni = 0; ni < 4; ++ni) {
      const int col = k0 + ni * 16 + l15;
      if (col < 1500) {
#pragma unroll
        for (int i = 0; i < 4; ++i) {
          const int row = w * 16 + l4 * 4 + i;
          wbase[(size_t)row * 1500 + col] = __expf(s[ni][i] - m_r[i]) * rinv[i];
        }
      }
    }
    __builtin_amdgcn_s_barrier();
  }
}

// ---------------------------------------------------------------------------
extern "C" void kernel_launch(void* const* d_in, const int* in_sizes, int n_in,
                              void* d_out, int out_size, void* d_ws, size_t ws_size,
                              hipStream_t stream) {
  const float* x  = (const float*)d_in[0];
  const float* k  = (const float*)d_in[1];
  const float* v  = (const float*)d_in[2];
  const float* Wq = (const float*)d_in[3];
  const float* bq = (const float*)d_in[4];
  const float* Wo = (const float*)d_in[5];
  const float* bo = (const float*)d_in[6];
  float* out  = (float*)d_out;
  float* wout = out + (size_t)8 * 448 * 1280;

  char* ws = (char*)d_ws;
  unsigned short* xb  = (unsigned short*)(ws);
  unsigned short* wqb = (unsigned short*)(ws + 9175040);
  unsigned short* wob = (unsigned short*)(ws + 12451840);
  unsigned short* kb  = (unsigned short*)(ws + 15728640);
  unsigned short* vbt = (unsigned short*)(ws + 46448640);
  unsigned short* qs  = (unsigned short*)(ws + 77905920);
  unsigned short* ao  = (unsigned short*)(ws + 87080960);
  float* ml           = (float*)(ws + 96256000);

  cvt_kernel<<<2048, 256, 0, stream>>>(x, Wq, Wo, k, xb);
  vt_kernel<<<1920, 256, 0, stream>>>(v, vbt);

  gemm_bt<0><<<280, 256, 0, stream>>>(xb, wqb, bq, (void*)qs, 3584, 1280, 1280, 0.125f);

  attn_kernel<<<8 * 20 * 7, 256, 0, stream>>>(qs, kb, vbt, ao, ml);

  gemm_bt<1><<<280, 256, 0, stream>>>(ao, wob, bo, (void*)out, 3584, 1280, 1280, 1.0f);

  weights_kernel<<<8 * 3 * 7, 256, 0, stream>>>(qs, kb, ml, wout);
}